// Round 20
// baseline (355.588 us; speedup 1.0000x reference)
//
#include <hip/hip_runtime.h>
#include <hip/hip_bf16.h>
#include <cstdint>

#define N_NODES 8192
#define N_EDGES 131072
#define NTOT 139264          // N_NODES + N_EDGES
#define H 128

typedef __attribute__((ext_vector_type(8))) short short8;
typedef __attribute__((ext_vector_type(4))) float floatx4;

__device__ __forceinline__ ushort f2bf(float f) {
    union { float f; uint32_t u; } v; v.f = f;
    uint32_t r = v.u + 0x7fffu + ((v.u >> 16) & 1u);   // RNE
    return (ushort)(r >> 16);
}
__device__ __forceinline__ float bf2f(ushort u) {
    union { uint32_t u; float f; } v; v.u = ((uint32_t)u) << 16;
    return v.f;
}
__device__ __forceinline__ float bflo(uint u) { union { uint32_t u; float f; } v; v.u = u << 16; return v.f; }
__device__ __forceinline__ float bfhi(uint u) { union { uint32_t u; float f; } v; v.u = u & 0xffff0000u; return v.f; }
__device__ __forceinline__ uint packbf(float a, float b) { return (uint)f2bf(a) | ((uint)f2bf(b) << 16); }

__device__ __forceinline__ float fsig(float x) { return __builtin_amdgcn_rcpf(1.f + __expf(-x)); }
__device__ __forceinline__ float ftanh(float x) { return fmaf(2.f, fsig(2.f * x), -1.f); }

__device__ __forceinline__ short8 lds_load8(const ushort* p) {
    union { short8 s; uint2 u[2]; } r;
    r.u[0] = *(const uint2*)p;
    r.u[1] = *(const uint2*)(p + 4);
    return r.s;
}
__device__ __forceinline__ short8 glb_load8(const ushort* p) {
    union { short8 s; uint4 u; } r;
    r.u = *(const uint4*)p;
    return r.s;
}
__device__ __forceinline__ floatx4 mfma16(short8 a, short8 b, floatx4 c) {
    return __builtin_amdgcn_mfma_f32_16x16x32_bf16(a, b, c, 0, 0, 0);
}

// ---------------------------------------------------------------------------
// Setup: Wb bf16 convert | Wci (layer-2 folded conv) | wh01 | wci01 |
// deg/deg2 zeroing.
// Wb offsets: WI 32768 | WH 81920 | M1 131072 | M2 147456 | M3 163840 |
//   R1 172032 | R2 180224 | end 196608.
// ---------------------------------------------------------------------------
__global__ __launch_bounds__(256) void k_setup(
    const float* __restrict__ convW, const float* __restrict__ wi, const float* __restrict__ wh,
    const float* __restrict__ m1, const float* __restrict__ m2, const float* __restrict__ m3,
    const float* __restrict__ r1, const float* __restrict__ r2,
    ushort* __restrict__ W, ushort* __restrict__ Wci,
    float* __restrict__ wh01, float* __restrict__ wci01,
    int* __restrict__ deg, int* __restrict__ deg2)
{
    int idx = blockIdx.x * 256 + threadIdx.x;
    if (idx < 196608) {
        if (idx < 32768) { W[idx] = 0; return; }
        float v;
        if (idx < 81920)       v = wi[idx - 32768];
        else if (idx < 131072) v = wh[idx - 81920];
        else if (idx < 147456) { int t = idx - 131072; int n = t >> 7, k = t & 127; v = m1[k * 128 + n]; }
        else if (idx < 163840) { int t = idx - 147456; int n = t >> 7, k = t & 127; v = m2[k * 128 + n]; }
        else if (idx < 172032) { int t = idx - 163840; int n = t >> 7, k = t & 127; v = m3[k * 64 + n];  }
        else if (idx < 180224) { int t = idx - 172032; int n = t >> 6, k = t & 63;  v = r1[k * 128 + n]; }
        else                   { int t = idx - 180224; int n = t >> 7, k = t & 127; v = r2[k * 128 + n]; }
        W[idx] = f2bf(v);
    } else if (idx < 245760) {                   // Wci for layer 2 (l=1)
        int t = idx - 196608;                    // 384*128
        int n = t >> 7, k = t & 127;
        const float* wc = convW + 16384 + k * 128;
        const float* wr = wi + n * 128;
        float s = 0.f;
        #pragma unroll 8
        for (int j = 0; j < 128; ++j) s = fmaf(wc[j], wr[j], s);
        Wci[t] = f2bf(s);
    } else if (idx < 246528) {                   // wh01[n] = wh[(n>>1)*128 + (n&1)]
        int n = idx - 245760;
        wh01[n] = wh[(n >> 1) * 128 + (n & 1)];
    } else if (idx < 247296) {                   // wci01 (l=0, k=0,1)
        int m = idx - 246528;
        int c = m >> 1, wsel = m & 1;
        const float* wc = convW + wsel * 128;
        const float* wr = wi + c * 128;
        float s = 0.f;
        #pragma unroll 8
        for (int j = 0; j < 128; ++j) s = fmaf(wc[j], wr[j], s);
        wci01[m] = s;
    } else if (idx < 263680) {                   // deg/deg2 zero
        int i = idx - 247296;
        if (i < 8192) deg[i] = 0;
        else deg2[i - 8192] = 0;
    }
}

// ---------------------------------------------------------------------------
// CSR build
// ---------------------------------------------------------------------------
__global__ __launch_bounds__(256) void k_deg_count(const int* __restrict__ row, const int* __restrict__ col,
                                                   int* __restrict__ deg, int* __restrict__ deg2) {
    int e = blockIdx.x * 256 + threadIdx.x;
    atomicAdd(&deg[row[e]], 1);
    atomicAdd(&deg[col[e]], 1);
    atomicAdd(&deg2[row[e]], 1);
}

__global__ __launch_bounds__(256) void k_scan(const int* __restrict__ deg, int* __restrict__ start, int* __restrict__ cur,
                                              const int* __restrict__ deg2, int* __restrict__ start2, int* __restrict__ cur2) {
    __shared__ int s1[256], s2[256];
    int tid = threadIdx.x, base = tid * 32;
    int a = 0, b = 0;
    for (int i = 0; i < 32; ++i) { a += deg[base + i]; b += deg2[base + i]; }
    s1[tid] = a; s2[tid] = b;
    __syncthreads();
    if (tid == 0) {
        int acc = 0, acc2 = 0;
        for (int i = 0; i < 256; ++i) {
            int t = s1[i]; s1[i] = acc; acc += t;
            int u = s2[i]; s2[i] = acc2; acc2 += u;
        }
    }
    __syncthreads();
    int off = s1[tid], off2 = s2[tid];
    for (int i = 0; i < 32; ++i) {
        start[base + i] = off;  cur[base + i] = off;   off += deg[base + i];
        start2[base + i] = off2; cur2[base + i] = off2; off2 += deg2[base + i];
    }
}

__global__ __launch_bounds__(256) void k_fill(const int* __restrict__ row, const int* __restrict__ col,
                                              int* __restrict__ cur, int* __restrict__ cur2,
                                              int* __restrict__ list, int* __restrict__ list2) {
    int e = blockIdx.x * 256 + threadIdx.x;
    int p = atomicAdd(&cur[row[e]], 1);  list[p] = e;
    int q = atomicAdd(&cur[col[e]], 1);  list[q] = e;
    int r2 = atomicAdd(&cur2[row[e]], 1); list2[r2] = e;
}

// ---------------------------------------------------------------------------
// Determinism pass: one WAVE per segment, STABLE rank-sort (handles duplicate
// edge ids from self-pair edges).  sj from the sorted copy, fixed pattern.
// ---------------------------------------------------------------------------
#define SORT_BUF 256
__global__ __launch_bounds__(256) void k_sort(
    const int* __restrict__ start, const int* __restrict__ deg,
    const int* __restrict__ start2, const int* __restrict__ deg2,
    int* __restrict__ list, int* __restrict__ list2,
    const float* __restrict__ jvals, float* __restrict__ sj)
{
    __shared__ int bufU[4][SORT_BUF];
    __shared__ int bufS[4][SORT_BUF];
    const int wv = threadIdx.x >> 6, lane = threadIdx.x & 63;
    const int task = blockIdx.x * 4 + wv;            // 0..16383
    const bool second = task >= 8192;
    const int node = second ? task - 8192 : task;
    const int s = second ? start2[node] : start[node];
    const int d = second ? deg2[node] : deg[node];
    int* L = second ? list2 : list;
    int* BU = bufU[wv];
    int* BS = bufS[wv];

    for (int i = lane; i < d && i < SORT_BUF; i += 64) BU[i] = L[s + i];
    __syncthreads();
    if (d <= SORT_BUF) {
        for (int i = lane; i < d; i += 64) {
            int v = BU[i];
            int rank = 0;
            for (int j = 0; j < d; ++j)
                rank += (BU[j] < v) || (BU[j] == v && j < i);   // stable tie-break
            L[s + rank] = v;
            BS[rank] = v;
        }
    } else if (lane == 0) {                          // unreachable fallback
        for (int a = 1; a < d; ++a) {
            int v = L[s + a]; int b = a - 1;
            while (b >= 0 && L[s + b] > v) { L[s + b + 1] = L[s + b]; --b; }
            L[s + b + 1] = v;
        }
    }
    __syncthreads();
    if (!second) {                                   // sj from sorted copy
        float a = 0.f;
        if (d <= SORT_BUF) {
            for (int i = lane; i < d; i += 64) a += jvals[BS[i]];
        } else if (lane == 0) {
            for (int i = 0; i < d; ++i) a += jvals[L[s + i]];
        }
        for (int off = 32; off; off >>= 1) a += __shfl_down(a, off);
        if (lane == 0) sj[node] = a;
    }
}

// ---------------------------------------------------------------------------
// Layer-1 closed forms, fused (X0 nodes = 0; X0 factors = [1, jv, 0...]).
// ---------------------------------------------------------------------------
__global__ __launch_bounds__(256) void k_l1(
    const float* __restrict__ jvals, const float* __restrict__ wh01,
    const int* __restrict__ deg, const float* __restrict__ sj, const float* __restrict__ wci01,
    const float* __restrict__ bi, const float* __restrict__ bh, ushort* __restrict__ X1)
{
    int idx = blockIdx.x * 256 + threadIdx.x;     // (N_EDGES+N_NODES)*64
    if (idx < N_EDGES * 64) {
        int e = idx >> 6, cp = idx & 63;
        float jv = jvals[e];
        float res[2];
        #pragma unroll
        for (int t = 0; t < 2; ++t) {
            int c = 2 * cp + t;
            float ghr = fmaf(jv, wh01[c * 2 + 1], wh01[c * 2]) + bh[c];
            float ghz = fmaf(jv, wh01[(128 + c) * 2 + 1], wh01[(128 + c) * 2]) + bh[128 + c];
            float ghn = fmaf(jv, wh01[(256 + c) * 2 + 1], wh01[(256 + c) * 2]) + bh[256 + c];
            float r = fsig(bi[c] + ghr);
            float z = fsig(bi[128 + c] + ghz);
            float nn = ftanh(fmaf(r, ghn, bi[256 + c]));
            float x0 = (c == 0) ? 1.f : (c == 1 ? jv : 0.f);
            res[t] = (1.f - z) * nn + z * x0;
        }
        *(uint*)(X1 + (size_t)(N_NODES + e) * H + 2 * cp) = packbf(res[0], res[1]);
    } else {
        int j = idx - N_EDGES * 64;
        int n = j >> 6, cp = j & 63;
        float d = (float)deg[n], s = sj[n];
        float res[2];
        #pragma unroll
        for (int t = 0; t < 2; ++t) {
            int c = 2 * cp + t;
            float gir = fmaf(s, wci01[c * 2 + 1], fmaf(d, wci01[c * 2], bi[c]));
            float giz = fmaf(s, wci01[(128 + c) * 2 + 1], fmaf(d, wci01[(128 + c) * 2], bi[128 + c]));
            float gin = fmaf(s, wci01[(256 + c) * 2 + 1], fmaf(d, wci01[(256 + c) * 2], bi[256 + c]));
            float r = fsig(gir + bh[c]);
            float z = fsig(giz + bh[128 + c]);
            float nn = ftanh(fmaf(r, bh[256 + c], gin));
            res[t] = (1.f - z) * nn;              // x_old = 0
        }
        *(uint*)(X1 + (size_t)n * H + 2 * cp) = packbf(res[0], res[1]);
    }
}

// Pn (node rows only) = sum over incident factor rows of X1 (sorted order).
// Unroll-4: 4 independent gathers in flight; fixed tree (a0+a1)+(a2+a3).
__global__ __launch_bounds__(256) void k_agg_nodes(uint* __restrict__ Pn, const uint* __restrict__ X,
                                                   const int* __restrict__ start, const int* __restrict__ deg,
                                                   const int* __restrict__ list) {
    int node = blockIdx.x * 4 + (threadIdx.x >> 6);
    int lane = threadIdx.x & 63;
    int s = start[node], d = deg[node];
    float a0 = 0.f, b0 = 0.f, a1 = 0.f, b1 = 0.f;
    float a2 = 0.f, b2 = 0.f, a3 = 0.f, b3 = 0.f;
    int i = 0;
    for (; i + 3 < d; i += 4) {
        uint v0 = X[(size_t)(N_NODES + list[s + i]) * 64 + lane];
        uint v1 = X[(size_t)(N_NODES + list[s + i + 1]) * 64 + lane];
        uint v2 = X[(size_t)(N_NODES + list[s + i + 2]) * 64 + lane];
        uint v3 = X[(size_t)(N_NODES + list[s + i + 3]) * 64 + lane];
        a0 += bflo(v0); b0 += bfhi(v0);
        a1 += bflo(v1); b1 += bfhi(v1);
        a2 += bflo(v2); b2 += bfhi(v2);
        a3 += bflo(v3); b3 += bfhi(v3);
    }
    for (; i < d; ++i) {
        uint v0 = X[(size_t)(N_NODES + list[s + i]) * 64 + lane];
        a0 += bflo(v0); b0 += bfhi(v0);
    }
    Pn[(size_t)node * 64 + lane] = packbf((a0 + a1) + (a2 + a3), (b0 + b1) + (b2 + b3));
}

// node_msgs = segment_sum(msgs, row) via row-CSR (sorted); msgs bf16 -> bf16.
// Unroll-4, fixed reduction tree.
__global__ __launch_bounds__(256) void k_nm_gather(ushort* __restrict__ nmb, const ushort* __restrict__ msgs,
                                                   const int* __restrict__ start2, const int* __restrict__ deg2,
                                                   const int* __restrict__ list2) {
    int node = blockIdx.x * 4 + (threadIdx.x >> 6);
    int lane = threadIdx.x & 63;
    int s = start2[node], d = deg2[node];
    float a0 = 0.f, a1 = 0.f, a2 = 0.f, a3 = 0.f;
    int i = 0;
    for (; i + 3 < d; i += 4) {
        a0 += bf2f(msgs[(size_t)list2[s + i] * 64 + lane]);
        a1 += bf2f(msgs[(size_t)list2[s + i + 1] * 64 + lane]);
        a2 += bf2f(msgs[(size_t)list2[s + i + 2] * 64 + lane]);
        a3 += bf2f(msgs[(size_t)list2[s + i + 3] * 64 + lane]);
    }
    for (; i < d; ++i) a0 += bf2f(msgs[(size_t)list2[s + i] * 64 + lane]);
    nmb[(size_t)node * 64 + lane] = f2bf((a0 + a1) + (a2 + a3));
}

__global__ __launch_bounds__(256) void k_logits(const ushort* __restrict__ hr2, const float* __restrict__ W3,
                                                const float* __restrict__ b3, float* __restrict__ out) {
    int r = blockIdx.x * 4 + (threadIdx.x >> 6);
    int lane = threadIdx.x & 63;
    float l0 = 0.f, l1 = 0.f;
    for (int k = lane; k < H; k += 64) {
        float hv = bf2f(hr2[(size_t)r * H + k]);
        l0 = fmaf(hv, W3[k * 2 + 0], l0);
        l1 = fmaf(hv, W3[k * 2 + 1], l1);
    }
    for (int off = 32; off; off >>= 1) { l0 += __shfl_down(l0, off); l1 += __shfl_down(l1, off); }
    if (lane == 0) {
        l0 += b3[0]; l1 += b3[1];
        float mx = fmaxf(l0, l1);
        float e0 = __expf(l0 - mx), e1 = __expf(l1 - mx), s = e0 + e1;
        out[r * 2 + 0] = e0 / s;
        out[r * 2 + 1] = e1 / s;
    }
}

// ---------------------------------------------------------------------------
// MFMA GEMM (readout): single-barrier full-tile staging.
// ---------------------------------------------------------------------------
template<int BN, bool AF32, bool RELU, bool OUTF32>
__global__ __launch_bounds__(256) void k_gemm2(
    const void* __restrict__ Aptr, const ushort* __restrict__ Bt,
    const float* __restrict__ bias, void* __restrict__ Cptr, int K, int lda)
{
    constexpr int BM = 128, LK = 136;
    constexpr int MI = (BN == 128) ? 4 : 2;
    constexpr int NI = 4;
    __shared__ ushort As[BM * LK];
    __shared__ ushort Bs[BN * LK];
    const int tid = threadIdx.x;
    const size_t row0 = (size_t)blockIdx.x * BM;
    const int kpc = K >> 3;

    if (AF32) {
        const float* A = (const float*)Aptr;
        for (int id = tid; id < BM * kpc; id += 256) {
            int m = id / kpc, kc = id - m * kpc;
            float4 v0 = *(const float4*)(A + (row0 + m) * lda + kc * 8);
            float4 v1 = *(const float4*)(A + (row0 + m) * lda + kc * 8 + 4);
            uint4 u;
            u.x = packbf(v0.x, v0.y); u.y = packbf(v0.z, v0.w);
            u.z = packbf(v1.x, v1.y); u.w = packbf(v1.z, v1.w);
            *(uint4*)&As[m * LK + kc * 8] = u;
        }
    } else {
        const ushort* A = (const ushort*)Aptr;
        for (int id = tid; id < BM * kpc; id += 256) {
            int m = id / kpc, kc = id - m * kpc;
            *(uint4*)&As[m * LK + kc * 8] = *(const uint4*)(A + (row0 + m) * (size_t)lda + kc * 8);
        }
    }
    for (int id = tid; id < BN * kpc; id += 256) {
        int slot = id / kpc, kc = id - slot * kpc;
        int gcol = (slot & ~63) + 4 * (slot & 15) + ((slot >> 4) & 3);
        *(uint4*)&Bs[slot * LK + kc * 8] = *(const uint4*)(Bt + (size_t)gcol * K + kc * 8);
    }
    __syncthreads();

    const int w = tid >> 6, lane = tid & 63, quad = lane >> 4, l15 = lane & 15;
    const int wr = (BN == 128) ? (w >> 1) * 64 : w * 32;
    const int wc = (BN == 128) ? (w & 1) * 64 : 0;

    floatx4 acc[MI][NI];
    #pragma unroll
    for (int i = 0; i < MI; ++i)
        #pragma unroll
        for (int j = 0; j < NI; ++j) acc[i][j] = (floatx4)0.f;

    for (int k0 = 0; k0 < K; k0 += 32) {
        short8 a[MI], b[NI];
        #pragma unroll
        for (int mi = 0; mi < MI; ++mi) a[mi] = lds_load8(&As[(wr + mi * 16 + l15) * LK + k0 + quad * 8]);
        #pragma unroll
        for (int ni = 0; ni < NI; ++ni) b[ni] = lds_load8(&Bs[(wc + ni * 16 + l15) * LK + k0 + quad * 8]);
        #pragma unroll
        for (int mi = 0; mi < MI; ++mi)
            #pragma unroll
            for (int ni = 0; ni < NI; ++ni)
                acc[mi][ni] = mfma16(a[mi], b[ni], acc[mi][ni]);
    }

    float bv[NI];
    #pragma unroll
    for (int ni = 0; ni < NI; ++ni) bv[ni] = bias ? bias[wc + 4 * l15 + ni] : 0.f;
    #pragma unroll
    for (int mi = 0; mi < MI; ++mi) {
        #pragma unroll
        for (int reg = 0; reg < 4; ++reg) {
            size_t r = row0 + wr + mi * 16 + quad * 4 + reg;
            float v[NI];
            #pragma unroll
            for (int ni = 0; ni < NI; ++ni) {
                v[ni] = acc[mi][ni][reg] + bv[ni];
                if (RELU) v[ni] = fmaxf(v[ni], 0.f);
            }
            if (OUTF32) {
                float4 o = make_float4(v[0], v[1], v[2], v[3]);
                *(float4*)((float*)Cptr + r * BN + wc + 4 * l15) = o;
            } else {
                uint2 o = make_uint2(packbf(v[0], v[1]), packbf(v[2], v[3]));
                *(uint2*)((ushort*)Cptr + r * BN + wc + 4 * l15) = o;
            }
        }
    }
}

// ---------------------------------------------------------------------------
// GRU v10 (layer 2): R17 structure + software-pipelined A-gathers.  All 16
// (factor) / 8 (node, h=1) k-chunk global loads are hoisted into register
// arrays AHEAD of the MFMA loop -> 16 outstanding loads per wave instead of
// 4; one gather latency per phase instead of four.  MFMA issue order and
// operand values unchanged -> bit-identical output.
// __launch_bounds__(512,3): VGPR cap ~170 for the ~128 needed (no spill).
// ---------------------------------------------------------------------------
__global__ __launch_bounds__(512, 3) void k_gru10(
    const ushort* __restrict__ Pn, const ushort* __restrict__ Xin, ushort* __restrict__ Xout,
    const int* __restrict__ row, const int* __restrict__ col,
    const ushort* __restrict__ WCI, const ushort* __restrict__ WH,
    const float* __restrict__ bi, const float* __restrict__ bh)
{
    constexpr int LK = 136;
    __shared__ ushort Ws[3 * 64 * LK];     // 52224 B
    const int tid = threadIdx.x;
    const int bid = blockIdx.x;
    const int u = bid & 7, v = bid >> 3;
    const int c0 = (v & 1) * 64;
    const int rowblk = (v >> 1) * 8 + u;
    const size_t brow0 = (size_t)rowblk * 128;
    const bool isFac = rowblk >= (N_NODES / 128);
    const int w = tid >> 6, lane = tid & 63, quad = lane >> 4, l15 = lane & 15;
    const int ch = w & 1;
    const size_t row0 = brow0 + (w >> 1) * 32;
    const int cb = c0 + ch * 32;

    int srcR[2], srcC[2];
    if (isFac) {
        #pragma unroll
        for (int mi = 0; mi < 2; ++mi) {
            int e = (int)(row0 + mi * 16 + l15) - N_NODES;
            srcR[mi] = row[e];
            srcC[mi] = col[e];
        }
    }

    floatx4 accR[2][2], accZ[2][2], accI[2][2], accHN[2][2];
    #pragma unroll
    for (int i = 0; i < 2; ++i)
        #pragma unroll
        for (int j = 0; j < 2; ++j) {
            accR[i][j] = (floatx4)0.f; accZ[i][j] = (floatx4)0.f;
            accI[i][j] = (floatx4)0.f; accHN[i][j] = (floatx4)0.f;
        }

    #pragma unroll
    for (int h = 0; h < 2; ++h) {
        if (h) __syncthreads();
        const ushort* Wsrc = h ? WH : WCI;
        for (int id = tid; id < 3072; id += 512) {
            int kc = id & 15, slot = (id >> 4) & 63, s = id >> 10;
            int w32 = slot & 31;
            int gcol = c0 + (slot >> 5) * 32 + 2 * (w32 & 15) + (w32 >> 4);
            *(uint4*)&Ws[(s * 64 + slot) * LK + kc * 8] =
                *(const uint4*)(Wsrc + (size_t)(s * 128 + gcol) * 128 + kc * 8);
        }
        __syncthreads();
        if (h == 0) {
            if (isFac) {
                // hoisted: all 16 gathers issued before any MFMA of this phase
                short8 ar[4][2], ac[4][2];
                #pragma unroll
                for (int k4 = 0; k4 < 4; ++k4)
                    #pragma unroll
                    for (int mi = 0; mi < 2; ++mi) {
                        ar[k4][mi] = glb_load8(Xin + (size_t)srcR[mi] * H + k4 * 32 + quad * 8);
                        ac[k4][mi] = glb_load8(Xin + (size_t)srcC[mi] * H + k4 * 32 + quad * 8);
                    }
                #pragma unroll
                for (int k4 = 0; k4 < 4; ++k4) {
                    const int k0 = k4 * 32;
                    #pragma unroll
                    for (int s = 0; s < 3; ++s) {
                        short8 b[2];
                        #pragma unroll
                        for (int ni = 0; ni < 2; ++ni)
                            b[ni] = lds_load8(&Ws[(s * 64 + ch * 32 + ni * 16 + l15) * LK + k0 + quad * 8]);
                        #pragma unroll
                        for (int mi = 0; mi < 2; ++mi)
                            #pragma unroll
                            for (int ni = 0; ni < 2; ++ni) {
                                if (s == 0) { accR[mi][ni] = mfma16(ar[k4][mi], b[ni], accR[mi][ni]);
                                              accR[mi][ni] = mfma16(ac[k4][mi], b[ni], accR[mi][ni]); }
                                else if (s == 1) { accZ[mi][ni] = mfma16(ar[k4][mi], b[ni], accZ[mi][ni]);
                                                   accZ[mi][ni] = mfma16(ac[k4][mi], b[ni], accZ[mi][ni]); }
                                else { accI[mi][ni] = mfma16(ar[k4][mi], b[ni], accI[mi][ni]);
                                       accI[mi][ni] = mfma16(ac[k4][mi], b[ni], accI[mi][ni]); }
                            }
                    }
                }
            } else {
                short8 a[4][2];
                #pragma unroll
                for (int k4 = 0; k4 < 4; ++k4)
                    #pragma unroll
                    for (int mi = 0; mi < 2; ++mi)
                        a[k4][mi] = glb_load8(Pn + (row0 + mi * 16 + l15) * H + k4 * 32 + quad * 8);
                #pragma unroll
                for (int k4 = 0; k4 < 4; ++k4) {
                    const int k0 = k4 * 32;
                    #pragma unroll
                    for (int s = 0; s < 3; ++s) {
                        short8 b[2];
                        #pragma unroll
                        for (int ni = 0; ni < 2; ++ni)
                            b[ni] = lds_load8(&Ws[(s * 64 + ch * 32 + ni * 16 + l15) * LK + k0 + quad * 8]);
                        #pragma unroll
                        for (int mi = 0; mi < 2; ++mi)
                            #pragma unroll
                            for (int ni = 0; ni < 2; ++ni) {
                                if (s == 0)      accR[mi][ni] = mfma16(a[k4][mi], b[ni], accR[mi][ni]);
                                else if (s == 1) accZ[mi][ni] = mfma16(a[k4][mi], b[ni], accZ[mi][ni]);
                                else             accI[mi][ni] = mfma16(a[k4][mi], b[ni], accI[mi][ni]);
                            }
                    }
                }
            }
        } else {
            short8 a[4][2];
            #pragma unroll
            for (int k4 = 0; k4 < 4; ++k4)
                #pragma unroll
                for (int mi = 0; mi < 2; ++mi)
                    a[k4][mi] = glb_load8(Xin + (row0 + mi * 16 + l15) * H + k4 * 32 + quad * 8);
            #pragma unroll
            for (int k4 = 0; k4 < 4; ++k4) {
                const int k0 = k4 * 32;
                #pragma unroll
                for (int s = 0; s < 3; ++s) {
                    short8 b[2];
                    #pragma unroll
                    for (int ni = 0; ni < 2; ++ni)
                        b[ni] = lds_load8(&Ws[(s * 64 + ch * 32 + ni * 16 + l15) * LK + k0 + quad * 8]);
                    #pragma unroll
                    for (int mi = 0; mi < 2; ++mi)
                        #pragma unroll
                        for (int ni = 0; ni < 2; ++ni) {
                            if (s == 0)      accR[mi][ni] = mfma16(a[k4][mi], b[ni], accR[mi][ni]);
                            else if (s == 1) accZ[mi][ni] = mfma16(a[k4][mi], b[ni], accZ[mi][ni]);
                            else             accHN[mi][ni] = mfma16(a[k4][mi], b[ni], accHN[mi][ni]);
                        }
                }
            }
        }
    }

    const int ce = cb + 2 * l15;
    float bir[2], biz[2], bin_[2], bhr[2], bhz[2], bhn[2];
    #pragma unroll
    for (int ni = 0; ni < 2; ++ni) {
        bir[ni] = bi[ce + ni]; biz[ni] = bi[128 + ce + ni]; bin_[ni] = bi[256 + ce + ni];
        bhr[ni] = bh[ce + ni]; bhz[ni] = bh[128 + ce + ni]; bhn[ni] = bh[256 + ce + ni];
    }
    #pragma unroll
    for (int mi = 0; mi < 2; ++mi)
        #pragma unroll
        for (int reg = 0; reg < 4; ++reg) {
            size_t r = row0 + mi * 16 + quad * 4 + reg;
            uint xo = *(const uint*)(Xin + r * H + ce);
            float xold[2] = { bflo(xo), bfhi(xo) };
            float res[2];
            #pragma unroll
            for (int ni = 0; ni < 2; ++ni) {
                float rs = accR[mi][ni][reg] + bir[ni] + bhr[ni];
                float zs = accZ[mi][ni][reg] + biz[ni] + bhz[ni];
                float rr = fsig(rs);
                float zz = fsig(zs);
                float nn = ftanh(accI[mi][ni][reg] + bin_[ni] + rr * (accHN[mi][ni][reg] + bhn[ni]));
                res[ni] = (1.f - zz) * nn + zz * xold[ni];
            }
            *(uint*)(Xout + r * H + ce) = packbf(res[0], res[1]);
        }
}

// ---------------------------------------------------------------------------
// Fused edge-MLP (R15 512-thread variant)
// ---------------------------------------------------------------------------
__global__ __launch_bounds__(512, 6) void k_mlp(
    const ushort* __restrict__ Xf, const ushort* __restrict__ W1, const ushort* __restrict__ W2,
    const ushort* __restrict__ W3, const float* __restrict__ b1, const float* __restrict__ b2,
    const float* __restrict__ b3, ushort* __restrict__ msgs)
{
    constexpr int LK = 132;
    __shared__ ushort T[128 * LK];
    __shared__ ushort Wv[64 * LK];
    const int tid = threadIdx.x;
    const size_t row0 = (size_t)blockIdx.x * 128;
    const int w = tid >> 6, lane = tid & 63, quad = lane >> 4, l15 = lane & 15;
    const int wr = w * 16;                 // 16 rows per wave

    for (int id = tid; id < 2048; id += 512) {
        int m = id >> 4, kc = (id & 15) * 8;
        *(uint4*)&T[m * LK + kc] = *(const uint4*)(Xf + (row0 + m) * H + kc);
    }

    #pragma unroll
    for (int stage = 0; stage < 3; ++stage) {
        const ushort* Wsrc = (stage == 0) ? W1 : (stage == 1) ? W2 : W3;
        const float* bias = (stage == 0) ? b1 : (stage == 1) ? b2 : b3;
        const int NCG = (stage == 2) ? 1 : 2;
        floatx4 acc[2][4];
        #pragma unroll
        for (int c = 0; c < 2; ++c)
            #pragma unroll
            for (int j = 0; j < 4; ++j) acc[c][j] = (floatx4)0.f;

        for (int cg = 0; cg < NCG; ++cg) {
            __syncthreads();
            for (int id = tid; id < 1024; id += 512) {
                int slot = id >> 4, kc = (id & 15) * 8;
                int gcol = cg * 64 + 4 * (slot & 15) + (slot >> 4);
                *(uint4*)&Wv[slot * LK + kc] = *(const uint4*)(Wsrc + (size_t)gcol * 128 + kc);
            }
            __syncthreads();
            for (int k0 = 0; k0 < 128; k0 += 32) {
                short8 a, b[4];
                a = lds_load8(&T[(wr + l15) * LK + k0 + quad * 8]);
                #pragma unroll
                for (int ni = 0; ni < 4; ++ni)
                    b[ni] = lds_load8(&Wv[(ni * 16 + l15) * LK + k0 + quad * 8]);
                #pragma unroll
                for (int ni = 0; ni < 4; ++ni)
                    acc[cg][ni] = mfma16(a, b[ni], acc[cg][ni]);
            }
        }
        __syncthreads();

        if (stage < 2) {
            #pragma unroll
            for (int cg = 0; cg < 2; ++cg) {
                float bv[4];
                #pragma unroll
                for (int ni = 0; ni < 4; ++ni) bv[ni] = bias[cg * 64 + 4 * l15 + ni];
                #pragma unroll
                for (int reg = 0; reg < 4; ++reg) {
                    int r = wr + quad * 4 + reg;
                    float v[4];
                    #pragma unroll
                    for (int ni = 0; ni < 4; ++ni)
                        v[ni] = fmaxf(acc[cg][ni][reg] + bv[ni], 0.f);
                    uint2 o = make_uint2(packbf(v[0], v[1]), packbf(v[2], v[3]));
                    *(uint2*)&T[r * LK + cg * 64 + 4 * l15] = o;
                }
            }
            __syncthreads();
        } else {
            float bv[4];
            #pragma unroll
            for (int ni = 0; ni < 4; ++ni) bv[ni] = bias[4 * l15 + ni];
            #pragma unroll
            for (int reg = 0; reg < 4; ++reg) {
                size_t r = row0 + wr + quad * 4 + reg;
                float v[4];
                #pragma unroll
                for (int ni = 0; ni < 4; ++ni) v[ni] = acc[0][ni][reg] + bv[ni];
                uint2 o = make_uint2(packbf(v[0], v[1]), packbf(v[2], v[3]));
                *(uint2*)(msgs + r * 64 + 4 * l15) = o;
            }
        }
    }
}

// ---------------------------------------------------------------------------
// Launch.
// ---------------------------------------------------------------------------
extern "C" void kernel_launch(void* const* d_in, const int* in_sizes, int n_in,
                              void* d_out, int out_size, void* d_ws, size_t ws_size,
                              hipStream_t stream) {
    (void)in_sizes; (void)n_in; (void)out_size;
    const float* jvals  = (const float*)d_in[0];
    const int*   row    = (const int*)d_in[2];
    const int*   col    = (const int*)d_in[3];
    const float* conv_W = (const float*)d_in[4];
    const float* gru_wi = (const float*)d_in[5];
    const float* gru_wh = (const float*)d_in[6];
    const float* gru_bi = (const float*)d_in[7];
    const float* gru_bh = (const float*)d_in[8];
    const float* mp_W1  = (const float*)d_in[9];
    const float* mp_b1  = (const float*)d_in[10];
    const float* mp_W2  = (const float*)d_in[11];
    const float* mp_b2  = (const float*)d_in[12];
    const float* mp_W3  = (const float*)d_in[13];
    const float* mp_b3  = (const float*)d_in[14];
    const float* ro_b1  = (const float*)d_in[16];
    const float* ro_b2  = (const float*)d_in[18];
    const float* ro_W3  = (const float*)d_in[19];
    const float* ro_b3  = (const float*)d_in[20];

    constexpr size_t OFF_XB  = 35651584ull;
    constexpr size_t OFF_P   = 71303168ull;
    constexpr size_t OFF_W   = 106954752ull;
    constexpr size_t OFF_WCI = 107347968ull;
    constexpr size_t OFF_NM  = 107544576ull;
    constexpr size_t OFF_HR1 = 109641728ull;
    constexpr size_t OFF_HR2 = 111738880ull;
    constexpr size_t OFF_CSR = 113836032ull;
    constexpr size_t OFF_L1  = 114032640ull;
    constexpr size_t OFF_L2  = 115081216ull;
    constexpr size_t OFF_SJ  = 115605504ull;
    constexpr size_t OFF_WH01  = 115638272ull;
    constexpr size_t OFF_WCI01 = 115641344ull;
    constexpr size_t WS_NEED = 115644416ull;
    if (ws_size < WS_NEED) return;

    char* ws = (char*)d_ws;
    ushort* X2   = (ushort*)ws;                 // layer-2 output
    ushort* X1   = (ushort*)(ws + OFF_XB);      // layer-1 output
    ushort* Pn   = (ushort*)(ws + OFF_P);       // node agg (2 MB)
    ushort* msgs = (ushort*)(ws + OFF_P);       // after gru10 (Pn dead)
    ushort* Wb   = (ushort*)(ws + OFF_W);
    ushort* Wci  = (ushort*)(ws + OFF_WCI);     // layer-2 folded conv (384x128)
    ushort* nmb  = (ushort*)(ws + OFF_NM);      // node_msgs, bf16
    ushort* hr1  = (ushort*)(ws + OFF_HR1);
    ushort* hr2  = (ushort*)(ws + OFF_HR2);
    int* deg    = (int*)(ws + OFF_CSR);
    int* start  = deg + 8192;
    int* cur    = deg + 16384;
    int* deg2   = deg + 24576;
    int* start2 = deg + 32768;
    int* cur2   = deg + 40960;
    int* list   = (int*)(ws + OFF_L1);
    int* list2  = (int*)(ws + OFF_L2);
    float* sj    = (float*)(ws + OFF_SJ);
    float* wh01  = (float*)(ws + OFF_WH01);
    float* wci01 = (float*)(ws + OFF_WCI01);

    dim3 blk(256);

    k_setup<<<1030, blk, 0, stream>>>(conv_W, gru_wi, gru_wh, mp_W1, mp_W2, mp_W3,
                                      (const float*)d_in[15], (const float*)d_in[17],
                                      Wb, Wci, wh01, wci01, deg, deg2);
    k_deg_count<<<N_EDGES / 256, blk, 0, stream>>>(row, col, deg, deg2);
    k_scan<<<1, blk, 0, stream>>>(deg, start, cur, deg2, start2, cur2);
    k_fill<<<N_EDGES / 256, blk, 0, stream>>>(row, col, cur, cur2, list, list2);
    k_sort<<<4096, blk, 0, stream>>>(start, deg, start2, deg2, list, list2, jvals, sj);

    // layer 1 (closed form, f32, fused)
    k_l1<<<(N_EDGES + N_NODES) * 64 / 256, blk, 0, stream>>>(jvals, wh01, deg, sj, wci01,
                                                             gru_bi, gru_bh, X1);

    // layer 2  (XCD-swizzled 1-D grid, 512-thread blocks, pipelined gathers)
    k_agg_nodes<<<N_NODES / 4, blk, 0, stream>>>((uint*)Pn, (const uint*)X1, start, deg, list);
    k_gru10<<<2 * (NTOT / 128), dim3(512), 0, stream>>>(Pn, X1, X2, row, col,
        Wci, Wb + 81920, gru_bi, gru_bh);

    // fused edge MLP -> msgs (bf16)
    k_mlp<<<N_EDGES / 128, dim3(512), 0, stream>>>(
        X2 + (size_t)N_NODES * H, Wb + 131072, Wb + 147456, Wb + 163840,
        mp_b1, mp_b2, mp_b3, msgs);

    // node_msgs = segment_sum(msgs, row) -> bf16
    k_nm_gather<<<N_NODES / 4, blk, 0, stream>>>(nmb, msgs, start2, deg2, list2);

    // readout
    k_gemm2<128, false, true, false><<<N_NODES / 128, blk, 0, stream>>>(
        nmb, Wb + 172032, ro_b1, hr1, 64, 64);
    k_gemm2<128, false, true, false><<<N_NODES / 128, blk, 0, stream>>>(
        hr1, Wb + 180224, ro_b2, hr2, 128, 128);
    k_logits<<<N_NODES / 4, blk, 0, stream>>>(hr2, ro_W3, ro_b3, (float*)d_out);
}

// Round 21
// 345.401 us; speedup vs baseline: 1.0295x; 1.0295x over previous
//
#include <hip/hip_runtime.h>
#include <hip/hip_bf16.h>
#include <cstdint>

#define N_NODES 8192
#define N_EDGES 131072
#define NTOT 139264          // N_NODES + N_EDGES
#define H 128

typedef __attribute__((ext_vector_type(8))) short short8;
typedef __attribute__((ext_vector_type(4))) float floatx4;

__device__ __forceinline__ ushort f2bf(float f) {
    union { float f; uint32_t u; } v; v.f = f;
    uint32_t r = v.u + 0x7fffu + ((v.u >> 16) & 1u);   // RNE
    return (ushort)(r >> 16);
}
__device__ __forceinline__ float bf2f(ushort u) {
    union { uint32_t u; float f; } v; v.u = ((uint32_t)u) << 16;
    return v.f;
}
__device__ __forceinline__ float bflo(uint u) { union { uint32_t u; float f; } v; v.u = u << 16; return v.f; }
__device__ __forceinline__ float bfhi(uint u) { union { uint32_t u; float f; } v; v.u = u & 0xffff0000u; return v.f; }
__device__ __forceinline__ uint packbf(float a, float b) { return (uint)f2bf(a) | ((uint)f2bf(b) << 16); }

__device__ __forceinline__ float fsig(float x) { return __builtin_amdgcn_rcpf(1.f + __expf(-x)); }
__device__ __forceinline__ float ftanh(float x) { return fmaf(2.f, fsig(2.f * x), -1.f); }

__device__ __forceinline__ short8 lds_load8(const ushort* p) {
    union { short8 s; uint2 u[2]; } r;
    r.u[0] = *(const uint2*)p;
    r.u[1] = *(const uint2*)(p + 4);
    return r.s;
}
__device__ __forceinline__ short8 glb_load8(const ushort* p) {
    union { short8 s; uint4 u; } r;
    r.u = *(const uint4*)p;
    return r.s;
}
__device__ __forceinline__ floatx4 mfma16(short8 a, short8 b, floatx4 c) {
    return __builtin_amdgcn_mfma_f32_16x16x32_bf16(a, b, c, 0, 0, 0);
}

// ---------------------------------------------------------------------------
// Setup: Wb bf16 convert | Wci (layer-2 folded conv) | wh01 | wci01 |
// deg/deg2 zeroing.
// Wb offsets: WI 32768 | WH 81920 | M1 131072 | M2 147456 | M3 163840 |
//   R1 172032 | R2 180224 | end 196608.
// ---------------------------------------------------------------------------
__global__ __launch_bounds__(256) void k_setup(
    const float* __restrict__ convW, const float* __restrict__ wi, const float* __restrict__ wh,
    const float* __restrict__ m1, const float* __restrict__ m2, const float* __restrict__ m3,
    const float* __restrict__ r1, const float* __restrict__ r2,
    ushort* __restrict__ W, ushort* __restrict__ Wci,
    float* __restrict__ wh01, float* __restrict__ wci01,
    int* __restrict__ deg, int* __restrict__ deg2)
{
    int idx = blockIdx.x * 256 + threadIdx.x;
    if (idx < 196608) {
        if (idx < 32768) { W[idx] = 0; return; }
        float v;
        if (idx < 81920)       v = wi[idx - 32768];
        else if (idx < 131072) v = wh[idx - 81920];
        else if (idx < 147456) { int t = idx - 131072; int n = t >> 7, k = t & 127; v = m1[k * 128 + n]; }
        else if (idx < 163840) { int t = idx - 147456; int n = t >> 7, k = t & 127; v = m2[k * 128 + n]; }
        else if (idx < 172032) { int t = idx - 163840; int n = t >> 7, k = t & 127; v = m3[k * 64 + n];  }
        else if (idx < 180224) { int t = idx - 172032; int n = t >> 6, k = t & 63;  v = r1[k * 128 + n]; }
        else                   { int t = idx - 180224; int n = t >> 7, k = t & 127; v = r2[k * 128 + n]; }
        W[idx] = f2bf(v);
    } else if (idx < 245760) {                   // Wci for layer 2 (l=1)
        int t = idx - 196608;                    // 384*128
        int n = t >> 7, k = t & 127;
        const float* wc = convW + 16384 + k * 128;
        const float* wr = wi + n * 128;
        float s = 0.f;
        #pragma unroll 8
        for (int j = 0; j < 128; ++j) s = fmaf(wc[j], wr[j], s);
        Wci[t] = f2bf(s);
    } else if (idx < 246528) {                   // wh01[n] = wh[(n>>1)*128 + (n&1)]
        int n = idx - 245760;
        wh01[n] = wh[(n >> 1) * 128 + (n & 1)];
    } else if (idx < 247296) {                   // wci01 (l=0, k=0,1)
        int m = idx - 246528;
        int c = m >> 1, wsel = m & 1;
        const float* wc = convW + wsel * 128;
        const float* wr = wi + c * 128;
        float s = 0.f;
        #pragma unroll 8
        for (int j = 0; j < 128; ++j) s = fmaf(wc[j], wr[j], s);
        wci01[m] = s;
    } else if (idx < 263680) {                   // deg/deg2 zero
        int i = idx - 247296;
        if (i < 8192) deg[i] = 0;
        else deg2[i - 8192] = 0;
    }
}

// ---------------------------------------------------------------------------
// CSR build
// ---------------------------------------------------------------------------
__global__ __launch_bounds__(256) void k_deg_count(const int* __restrict__ row, const int* __restrict__ col,
                                                   int* __restrict__ deg, int* __restrict__ deg2) {
    int e = blockIdx.x * 256 + threadIdx.x;
    atomicAdd(&deg[row[e]], 1);
    atomicAdd(&deg[col[e]], 1);
    atomicAdd(&deg2[row[e]], 1);
}

__global__ __launch_bounds__(256) void k_scan(const int* __restrict__ deg, int* __restrict__ start, int* __restrict__ cur,
                                              const int* __restrict__ deg2, int* __restrict__ start2, int* __restrict__ cur2) {
    __shared__ int s1[256], s2[256];
    int tid = threadIdx.x, base = tid * 32;
    int a = 0, b = 0;
    for (int i = 0; i < 32; ++i) { a += deg[base + i]; b += deg2[base + i]; }
    s1[tid] = a; s2[tid] = b;
    __syncthreads();
    if (tid == 0) {
        int acc = 0, acc2 = 0;
        for (int i = 0; i < 256; ++i) {
            int t = s1[i]; s1[i] = acc; acc += t;
            int u = s2[i]; s2[i] = acc2; acc2 += u;
        }
    }
    __syncthreads();
    int off = s1[tid], off2 = s2[tid];
    for (int i = 0; i < 32; ++i) {
        start[base + i] = off;  cur[base + i] = off;   off += deg[base + i];
        start2[base + i] = off2; cur2[base + i] = off2; off2 += deg2[base + i];
    }
}

__global__ __launch_bounds__(256) void k_fill(const int* __restrict__ row, const int* __restrict__ col,
                                              int* __restrict__ cur, int* __restrict__ cur2,
                                              int* __restrict__ list, int* __restrict__ list2) {
    int e = blockIdx.x * 256 + threadIdx.x;
    int p = atomicAdd(&cur[row[e]], 1);  list[p] = e;
    int q = atomicAdd(&cur[col[e]], 1);  list[q] = e;
    int r2 = atomicAdd(&cur2[row[e]], 1); list2[r2] = e;
}

// ---------------------------------------------------------------------------
// Determinism pass: one WAVE per segment, STABLE rank-sort (handles duplicate
// edge ids from self-pair edges).  sj from the sorted copy, fixed pattern.
// ---------------------------------------------------------------------------
#define SORT_BUF 256
__global__ __launch_bounds__(256) void k_sort(
    const int* __restrict__ start, const int* __restrict__ deg,
    const int* __restrict__ start2, const int* __restrict__ deg2,
    int* __restrict__ list, int* __restrict__ list2,
    const float* __restrict__ jvals, float* __restrict__ sj)
{
    __shared__ int bufU[4][SORT_BUF];
    __shared__ int bufS[4][SORT_BUF];
    const int wv = threadIdx.x >> 6, lane = threadIdx.x & 63;
    const int task = blockIdx.x * 4 + wv;            // 0..16383
    const bool second = task >= 8192;
    const int node = second ? task - 8192 : task;
    const int s = second ? start2[node] : start[node];
    const int d = second ? deg2[node] : deg[node];
    int* L = second ? list2 : list;
    int* BU = bufU[wv];
    int* BS = bufS[wv];

    for (int i = lane; i < d && i < SORT_BUF; i += 64) BU[i] = L[s + i];
    __syncthreads();
    if (d <= SORT_BUF) {
        for (int i = lane; i < d; i += 64) {
            int v = BU[i];
            int rank = 0;
            for (int j = 0; j < d; ++j)
                rank += (BU[j] < v) || (BU[j] == v && j < i);   // stable tie-break
            L[s + rank] = v;
            BS[rank] = v;
        }
    } else if (lane == 0) {                          // unreachable fallback
        for (int a = 1; a < d; ++a) {
            int v = L[s + a]; int b = a - 1;
            while (b >= 0 && L[s + b] > v) { L[s + b + 1] = L[s + b]; --b; }
            L[s + b + 1] = v;
        }
    }
    __syncthreads();
    if (!second) {                                   // sj from sorted copy
        float a = 0.f;
        if (d <= SORT_BUF) {
            for (int i = lane; i < d; i += 64) a += jvals[BS[i]];
        } else if (lane == 0) {
            for (int i = 0; i < d; ++i) a += jvals[L[s + i]];
        }
        for (int off = 32; off; off >>= 1) a += __shfl_down(a, off);
        if (lane == 0) sj[node] = a;
    }
}

// ---------------------------------------------------------------------------
// Layer-1 closed forms, fused (X0 nodes = 0; X0 factors = [1, jv, 0...]).
// ---------------------------------------------------------------------------
__global__ __launch_bounds__(256) void k_l1(
    const float* __restrict__ jvals, const float* __restrict__ wh01,
    const int* __restrict__ deg, const float* __restrict__ sj, const float* __restrict__ wci01,
    const float* __restrict__ bi, const float* __restrict__ bh, ushort* __restrict__ X1)
{
    int idx = blockIdx.x * 256 + threadIdx.x;     // (N_EDGES+N_NODES)*64
    if (idx < N_EDGES * 64) {
        int e = idx >> 6, cp = idx & 63;
        float jv = jvals[e];
        float res[2];
        #pragma unroll
        for (int t = 0; t < 2; ++t) {
            int c = 2 * cp + t;
            float ghr = fmaf(jv, wh01[c * 2 + 1], wh01[c * 2]) + bh[c];
            float ghz = fmaf(jv, wh01[(128 + c) * 2 + 1], wh01[(128 + c) * 2]) + bh[128 + c];
            float ghn = fmaf(jv, wh01[(256 + c) * 2 + 1], wh01[(256 + c) * 2]) + bh[256 + c];
            float r = fsig(bi[c] + ghr);
            float z = fsig(bi[128 + c] + ghz);
            float nn = ftanh(fmaf(r, ghn, bi[256 + c]));
            float x0 = (c == 0) ? 1.f : (c == 1 ? jv : 0.f);
            res[t] = (1.f - z) * nn + z * x0;
        }
        *(uint*)(X1 + (size_t)(N_NODES + e) * H + 2 * cp) = packbf(res[0], res[1]);
    } else {
        int j = idx - N_EDGES * 64;
        int n = j >> 6, cp = j & 63;
        float d = (float)deg[n], s = sj[n];
        float res[2];
        #pragma unroll
        for (int t = 0; t < 2; ++t) {
            int c = 2 * cp + t;
            float gir = fmaf(s, wci01[c * 2 + 1], fmaf(d, wci01[c * 2], bi[c]));
            float giz = fmaf(s, wci01[(128 + c) * 2 + 1], fmaf(d, wci01[(128 + c) * 2], bi[128 + c]));
            float gin = fmaf(s, wci01[(256 + c) * 2 + 1], fmaf(d, wci01[(256 + c) * 2], bi[256 + c]));
            float r = fsig(gir + bh[c]);
            float z = fsig(giz + bh[128 + c]);
            float nn = ftanh(fmaf(r, bh[256 + c], gin));
            res[t] = (1.f - z) * nn;              // x_old = 0
        }
        *(uint*)(X1 + (size_t)n * H + 2 * cp) = packbf(res[0], res[1]);
    }
}

// Pn (node rows only) = sum over incident factor rows of X1 (sorted order).
// Unroll-4: 4 independent gathers in flight; fixed tree (a0+a1)+(a2+a3).
__global__ __launch_bounds__(256) void k_agg_nodes(uint* __restrict__ Pn, const uint* __restrict__ X,
                                                   const int* __restrict__ start, const int* __restrict__ deg,
                                                   const int* __restrict__ list) {
    int node = blockIdx.x * 4 + (threadIdx.x >> 6);
    int lane = threadIdx.x & 63;
    int s = start[node], d = deg[node];
    float a0 = 0.f, b0 = 0.f, a1 = 0.f, b1 = 0.f;
    float a2 = 0.f, b2 = 0.f, a3 = 0.f, b3 = 0.f;
    int i = 0;
    for (; i + 3 < d; i += 4) {
        uint v0 = X[(size_t)(N_NODES + list[s + i]) * 64 + lane];
        uint v1 = X[(size_t)(N_NODES + list[s + i + 1]) * 64 + lane];
        uint v2 = X[(size_t)(N_NODES + list[s + i + 2]) * 64 + lane];
        uint v3 = X[(size_t)(N_NODES + list[s + i + 3]) * 64 + lane];
        a0 += bflo(v0); b0 += bfhi(v0);
        a1 += bflo(v1); b1 += bfhi(v1);
        a2 += bflo(v2); b2 += bfhi(v2);
        a3 += bflo(v3); b3 += bfhi(v3);
    }
    for (; i < d; ++i) {
        uint v0 = X[(size_t)(N_NODES + list[s + i]) * 64 + lane];
        a0 += bflo(v0); b0 += bfhi(v0);
    }
    Pn[(size_t)node * 64 + lane] = packbf((a0 + a1) + (a2 + a3), (b0 + b1) + (b2 + b3));
}

// node_msgs = segment_sum(msgs, row) via row-CSR (sorted); msgs bf16 -> bf16.
// Unroll-4, fixed reduction tree.
__global__ __launch_bounds__(256) void k_nm_gather(ushort* __restrict__ nmb, const ushort* __restrict__ msgs,
                                                   const int* __restrict__ start2, const int* __restrict__ deg2,
                                                   const int* __restrict__ list2) {
    int node = blockIdx.x * 4 + (threadIdx.x >> 6);
    int lane = threadIdx.x & 63;
    int s = start2[node], d = deg2[node];
    float a0 = 0.f, a1 = 0.f, a2 = 0.f, a3 = 0.f;
    int i = 0;
    for (; i + 3 < d; i += 4) {
        a0 += bf2f(msgs[(size_t)list2[s + i] * 64 + lane]);
        a1 += bf2f(msgs[(size_t)list2[s + i + 1] * 64 + lane]);
        a2 += bf2f(msgs[(size_t)list2[s + i + 2] * 64 + lane]);
        a3 += bf2f(msgs[(size_t)list2[s + i + 3] * 64 + lane]);
    }
    for (; i < d; ++i) a0 += bf2f(msgs[(size_t)list2[s + i] * 64 + lane]);
    nmb[(size_t)node * 64 + lane] = f2bf((a0 + a1) + (a2 + a3));
}

__global__ __launch_bounds__(256) void k_logits(const ushort* __restrict__ hr2, const float* __restrict__ W3,
                                                const float* __restrict__ b3, float* __restrict__ out) {
    int r = blockIdx.x * 4 + (threadIdx.x >> 6);
    int lane = threadIdx.x & 63;
    float l0 = 0.f, l1 = 0.f;
    for (int k = lane; k < H; k += 64) {
        float hv = bf2f(hr2[(size_t)r * H + k]);
        l0 = fmaf(hv, W3[k * 2 + 0], l0);
        l1 = fmaf(hv, W3[k * 2 + 1], l1);
    }
    for (int off = 32; off; off >>= 1) { l0 += __shfl_down(l0, off); l1 += __shfl_down(l1, off); }
    if (lane == 0) {
        l0 += b3[0]; l1 += b3[1];
        float mx = fmaxf(l0, l1);
        float e0 = __expf(l0 - mx), e1 = __expf(l1 - mx), s = e0 + e1;
        out[r * 2 + 0] = e0 / s;
        out[r * 2 + 1] = e1 / s;
    }
}

// ---------------------------------------------------------------------------
// MFMA GEMM (readout): single-barrier full-tile staging.
// ---------------------------------------------------------------------------
template<int BN, bool AF32, bool RELU, bool OUTF32>
__global__ __launch_bounds__(256) void k_gemm2(
    const void* __restrict__ Aptr, const ushort* __restrict__ Bt,
    const float* __restrict__ bias, void* __restrict__ Cptr, int K, int lda)
{
    constexpr int BM = 128, LK = 136;
    constexpr int MI = (BN == 128) ? 4 : 2;
    constexpr int NI = 4;
    __shared__ ushort As[BM * LK];
    __shared__ ushort Bs[BN * LK];
    const int tid = threadIdx.x;
    const size_t row0 = (size_t)blockIdx.x * BM;
    const int kpc = K >> 3;

    if (AF32) {
        const float* A = (const float*)Aptr;
        for (int id = tid; id < BM * kpc; id += 256) {
            int m = id / kpc, kc = id - m * kpc;
            float4 v0 = *(const float4*)(A + (row0 + m) * lda + kc * 8);
            float4 v1 = *(const float4*)(A + (row0 + m) * lda + kc * 8 + 4);
            uint4 u;
            u.x = packbf(v0.x, v0.y); u.y = packbf(v0.z, v0.w);
            u.z = packbf(v1.x, v1.y); u.w = packbf(v1.z, v1.w);
            *(uint4*)&As[m * LK + kc * 8] = u;
        }
    } else {
        const ushort* A = (const ushort*)Aptr;
        for (int id = tid; id < BM * kpc; id += 256) {
            int m = id / kpc, kc = id - m * kpc;
            *(uint4*)&As[m * LK + kc * 8] = *(const uint4*)(A + (row0 + m) * (size_t)lda + kc * 8);
        }
    }
    for (int id = tid; id < BN * kpc; id += 256) {
        int slot = id / kpc, kc = id - slot * kpc;
        int gcol = (slot & ~63) + 4 * (slot & 15) + ((slot >> 4) & 3);
        *(uint4*)&Bs[slot * LK + kc * 8] = *(const uint4*)(Bt + (size_t)gcol * K + kc * 8);
    }
    __syncthreads();

    const int w = tid >> 6, lane = tid & 63, quad = lane >> 4, l15 = lane & 15;
    const int wr = (BN == 128) ? (w >> 1) * 64 : w * 32;
    const int wc = (BN == 128) ? (w & 1) * 64 : 0;

    floatx4 acc[MI][NI];
    #pragma unroll
    for (int i = 0; i < MI; ++i)
        #pragma unroll
        for (int j = 0; j < NI; ++j) acc[i][j] = (floatx4)0.f;

    for (int k0 = 0; k0 < K; k0 += 32) {
        short8 a[MI], b[NI];
        #pragma unroll
        for (int mi = 0; mi < MI; ++mi) a[mi] = lds_load8(&As[(wr + mi * 16 + l15) * LK + k0 + quad * 8]);
        #pragma unroll
        for (int ni = 0; ni < NI; ++ni) b[ni] = lds_load8(&Bs[(wc + ni * 16 + l15) * LK + k0 + quad * 8]);
        #pragma unroll
        for (int mi = 0; mi < MI; ++mi)
            #pragma unroll
            for (int ni = 0; ni < NI; ++ni)
                acc[mi][ni] = mfma16(a[mi], b[ni], acc[mi][ni]);
    }

    float bv[NI];
    #pragma unroll
    for (int ni = 0; ni < NI; ++ni) bv[ni] = bias ? bias[wc + 4 * l15 + ni] : 0.f;
    #pragma unroll
    for (int mi = 0; mi < MI; ++mi) {
        #pragma unroll
        for (int reg = 0; reg < 4; ++reg) {
            size_t r = row0 + wr + mi * 16 + quad * 4 + reg;
            float v[NI];
            #pragma unroll
            for (int ni = 0; ni < NI; ++ni) {
                v[ni] = acc[mi][ni][reg] + bv[ni];
                if (RELU) v[ni] = fmaxf(v[ni], 0.f);
            }
            if (OUTF32) {
                float4 o = make_float4(v[0], v[1], v[2], v[3]);
                *(float4*)((float*)Cptr + r * BN + wc + 4 * l15) = o;
            } else {
                uint2 o = make_uint2(packbf(v[0], v[1]), packbf(v[2], v[3]));
                *(uint2*)((ushort*)Cptr + r * BN + wc + 4 * l15) = o;
            }
        }
    }
}

// ---------------------------------------------------------------------------
// GRU v6 (layer 2), session-best configuration: 512 threads, XCD-aware
// swizzled 1-D grid, LDS weight staging, per-chunk A-gathers.
// (All tested alternatives regressed: R11 phase-merge 128us, R13 fuse +9us,
// R16 1024-thr 99us, R18 no-LDS 172us, R20 hoisted gathers 100us.)
// ---------------------------------------------------------------------------
__global__ __launch_bounds__(512, 4) void k_gru6(
    const ushort* __restrict__ Pn, const ushort* __restrict__ Xin, ushort* __restrict__ Xout,
    const int* __restrict__ row, const int* __restrict__ col,
    const ushort* __restrict__ WCI, const ushort* __restrict__ WH,
    const float* __restrict__ bi, const float* __restrict__ bh)
{
    constexpr int LK = 136;
    __shared__ ushort Ws[3 * 64 * LK];     // 52224 B
    const int tid = threadIdx.x;
    const int bid = blockIdx.x;
    const int u = bid & 7, v = bid >> 3;
    const int c0 = (v & 1) * 64;
    const int rowblk = (v >> 1) * 8 + u;
    const size_t brow0 = (size_t)rowblk * 128;
    const bool isFac = rowblk >= (N_NODES / 128);
    const int w = tid >> 6, lane = tid & 63, quad = lane >> 4, l15 = lane & 15;
    const int ch = w & 1;
    const size_t row0 = brow0 + (w >> 1) * 32;
    const int cb = c0 + ch * 32;

    int srcR[2], srcC[2];
    if (isFac) {
        #pragma unroll
        for (int mi = 0; mi < 2; ++mi) {
            int e = (int)(row0 + mi * 16 + l15) - N_NODES;
            srcR[mi] = row[e];
            srcC[mi] = col[e];
        }
    }

    floatx4 accR[2][2], accZ[2][2], accI[2][2], accHN[2][2];
    #pragma unroll
    for (int i = 0; i < 2; ++i)
        #pragma unroll
        for (int j = 0; j < 2; ++j) {
            accR[i][j] = (floatx4)0.f; accZ[i][j] = (floatx4)0.f;
            accI[i][j] = (floatx4)0.f; accHN[i][j] = (floatx4)0.f;
        }

    #pragma unroll
    for (int h = 0; h < 2; ++h) {
        if (h) __syncthreads();
        const ushort* Wsrc = h ? WH : WCI;
        for (int id = tid; id < 3072; id += 512) {
            int kc = id & 15, slot = (id >> 4) & 63, s = id >> 10;
            int w32 = slot & 31;
            int gcol = c0 + (slot >> 5) * 32 + 2 * (w32 & 15) + (w32 >> 4);
            *(uint4*)&Ws[(s * 64 + slot) * LK + kc * 8] =
                *(const uint4*)(Wsrc + (size_t)(s * 128 + gcol) * 128 + kc * 8);
        }
        __syncthreads();
        if (h == 0) {
            if (isFac) {
                #pragma unroll
                for (int k4 = 0; k4 < 4; ++k4) {
                    const int k0 = k4 * 32;
                    short8 ar[2], ac[2];
                    #pragma unroll
                    for (int mi = 0; mi < 2; ++mi) {
                        ar[mi] = glb_load8(Xin + (size_t)srcR[mi] * H + k0 + quad * 8);
                        ac[mi] = glb_load8(Xin + (size_t)srcC[mi] * H + k0 + quad * 8);
                    }
                    #pragma unroll
                    for (int s = 0; s < 3; ++s) {
                        short8 b[2];
                        #pragma unroll
                        for (int ni = 0; ni < 2; ++ni)
                            b[ni] = lds_load8(&Ws[(s * 64 + ch * 32 + ni * 16 + l15) * LK + k0 + quad * 8]);
                        #pragma unroll
                        for (int mi = 0; mi < 2; ++mi)
                            #pragma unroll
                            for (int ni = 0; ni < 2; ++ni) {
                                if (s == 0) { accR[mi][ni] = mfma16(ar[mi], b[ni], accR[mi][ni]);
                                              accR[mi][ni] = mfma16(ac[mi], b[ni], accR[mi][ni]); }
                                else if (s == 1) { accZ[mi][ni] = mfma16(ar[mi], b[ni], accZ[mi][ni]);
                                                   accZ[mi][ni] = mfma16(ac[mi], b[ni], accZ[mi][ni]); }
                                else { accI[mi][ni] = mfma16(ar[mi], b[ni], accI[mi][ni]);
                                       accI[mi][ni] = mfma16(ac[mi], b[ni], accI[mi][ni]); }
                            }
                    }
                }
            } else {
                #pragma unroll
                for (int k4 = 0; k4 < 4; ++k4) {
                    const int k0 = k4 * 32;
                    short8 a[2];
                    #pragma unroll
                    for (int mi = 0; mi < 2; ++mi)
                        a[mi] = glb_load8(Pn + (row0 + mi * 16 + l15) * H + k0 + quad * 8);
                    #pragma unroll
                    for (int s = 0; s < 3; ++s) {
                        short8 b[2];
                        #pragma unroll
                        for (int ni = 0; ni < 2; ++ni)
                            b[ni] = lds_load8(&Ws[(s * 64 + ch * 32 + ni * 16 + l15) * LK + k0 + quad * 8]);
                        #pragma unroll
                        for (int mi = 0; mi < 2; ++mi)
                            #pragma unroll
                            for (int ni = 0; ni < 2; ++ni) {
                                if (s == 0)      accR[mi][ni] = mfma16(a[mi], b[ni], accR[mi][ni]);
                                else if (s == 1) accZ[mi][ni] = mfma16(a[mi], b[ni], accZ[mi][ni]);
                                else             accI[mi][ni] = mfma16(a[mi], b[ni], accI[mi][ni]);
                            }
                    }
                }
            }
        } else {
            #pragma unroll
            for (int k4 = 0; k4 < 4; ++k4) {
                const int k0 = k4 * 32;
                short8 a[2];
                #pragma unroll
                for (int mi = 0; mi < 2; ++mi)
                    a[mi] = glb_load8(Xin + (row0 + mi * 16 + l15) * H + k0 + quad * 8);
                #pragma unroll
                for (int s = 0; s < 3; ++s) {
                    short8 b[2];
                    #pragma unroll
                    for (int ni = 0; ni < 2; ++ni)
                        b[ni] = lds_load8(&Ws[(s * 64 + ch * 32 + ni * 16 + l15) * LK + k0 + quad * 8]);
                    #pragma unroll
                    for (int mi = 0; mi < 2; ++mi)
                        #pragma unroll
                        for (int ni = 0; ni < 2; ++ni) {
                            if (s == 0)      accR[mi][ni] = mfma16(a[mi], b[ni], accR[mi][ni]);
                            else if (s == 1) accZ[mi][ni] = mfma16(a[mi], b[ni], accZ[mi][ni]);
                            else             accHN[mi][ni] = mfma16(a[mi], b[ni], accHN[mi][ni]);
                        }
                }
            }
        }
    }

    const int ce = cb + 2 * l15;
    float bir[2], biz[2], bin_[2], bhr[2], bhz[2], bhn[2];
    #pragma unroll
    for (int ni = 0; ni < 2; ++ni) {
        bir[ni] = bi[ce + ni]; biz[ni] = bi[128 + ce + ni]; bin_[ni] = bi[256 + ce + ni];
        bhr[ni] = bh[ce + ni]; bhz[ni] = bh[128 + ce + ni]; bhn[ni] = bh[256 + ce + ni];
    }
    #pragma unroll
    for (int mi = 0; mi < 2; ++mi)
        #pragma unroll
        for (int reg = 0; reg < 4; ++reg) {
            size_t r = row0 + mi * 16 + quad * 4 + reg;
            uint xo = *(const uint*)(Xin + r * H + ce);
            float xold[2] = { bflo(xo), bfhi(xo) };
            float res[2];
            #pragma unroll
            for (int ni = 0; ni < 2; ++ni) {
                float rs = accR[mi][ni][reg] + bir[ni] + bhr[ni];
                float zs = accZ[mi][ni][reg] + biz[ni] + bhz[ni];
                float rr = fsig(rs);
                float zz = fsig(zs);
                float nn = ftanh(accI[mi][ni][reg] + bin_[ni] + rr * (accHN[mi][ni][reg] + bhn[ni]));
                res[ni] = (1.f - zz) * nn + zz * xold[ni];
            }
            *(uint*)(Xout + r * H + ce) = packbf(res[0], res[1]);
        }
}

// ---------------------------------------------------------------------------
// Fused edge-MLP (512-thread variant)
// ---------------------------------------------------------------------------
__global__ __launch_bounds__(512, 6) void k_mlp(
    const ushort* __restrict__ Xf, const ushort* __restrict__ W1, const ushort* __restrict__ W2,
    const ushort* __restrict__ W3, const float* __restrict__ b1, const float* __restrict__ b2,
    const float* __restrict__ b3, ushort* __restrict__ msgs)
{
    constexpr int LK = 132;
    __shared__ ushort T[128 * LK];
    __shared__ ushort Wv[64 * LK];
    const int tid = threadIdx.x;
    const size_t row0 = (size_t)blockIdx.x * 128;
    const int w = tid >> 6, lane = tid & 63, quad = lane >> 4, l15 = lane & 15;
    const int wr = w * 16;                 // 16 rows per wave

    for (int id = tid; id < 2048; id += 512) {
        int m = id >> 4, kc = (id & 15) * 8;
        *(uint4*)&T[m * LK + kc] = *(const uint4*)(Xf + (row0 + m) * H + kc);
    }

    #pragma unroll
    for (int stage = 0; stage < 3; ++stage) {
        const ushort* Wsrc = (stage == 0) ? W1 : (stage == 1) ? W2 : W3;
        const float* bias = (stage == 0) ? b1 : (stage == 1) ? b2 : b3;
        const int NCG = (stage == 2) ? 1 : 2;
        floatx4 acc[2][4];
        #pragma unroll
        for (int c = 0; c < 2; ++c)
            #pragma unroll
            for (int j = 0; j < 4; ++j) acc[c][j] = (floatx4)0.f;

        for (int cg = 0; cg < NCG; ++cg) {
            __syncthreads();
            for (int id = tid; id < 1024; id += 512) {
                int slot = id >> 4, kc = (id & 15) * 8;
                int gcol = cg * 64 + 4 * (slot & 15) + (slot >> 4);
                *(uint4*)&Wv[slot * LK + kc] = *(const uint4*)(Wsrc + (size_t)gcol * 128 + kc);
            }
            __syncthreads();
            for (int k0 = 0; k0 < 128; k0 += 32) {
                short8 a, b[4];
                a = lds_load8(&T[(wr + l15) * LK + k0 + quad * 8]);
                #pragma unroll
                for (int ni = 0; ni < 4; ++ni)
                    b[ni] = lds_load8(&Wv[(ni * 16 + l15) * LK + k0 + quad * 8]);
                #pragma unroll
                for (int ni = 0; ni < 4; ++ni)
                    acc[cg][ni] = mfma16(a, b[ni], acc[cg][ni]);
            }
        }
        __syncthreads();

        if (stage < 2) {
            #pragma unroll
            for (int cg = 0; cg < 2; ++cg) {
                float bv[4];
                #pragma unroll
                for (int ni = 0; ni < 4; ++ni) bv[ni] = bias[cg * 64 + 4 * l15 + ni];
                #pragma unroll
                for (int reg = 0; reg < 4; ++reg) {
                    int r = wr + quad * 4 + reg;
                    float v[4];
                    #pragma unroll
                    for (int ni = 0; ni < 4; ++ni)
                        v[ni] = fmaxf(acc[cg][ni][reg] + bv[ni], 0.f);
                    uint2 o = make_uint2(packbf(v[0], v[1]), packbf(v[2], v[3]));
                    *(uint2*)&T[r * LK + cg * 64 + 4 * l15] = o;
                }
            }
            __syncthreads();
        } else {
            float bv[4];
            #pragma unroll
            for (int ni = 0; ni < 4; ++ni) bv[ni] = bias[4 * l15 + ni];
            #pragma unroll
            for (int reg = 0; reg < 4; ++reg) {
                size_t r = row0 + wr + quad * 4 + reg;
                float v[4];
                #pragma unroll
                for (int ni = 0; ni < 4; ++ni) v[ni] = acc[0][ni][reg] + bv[ni];
                uint2 o = make_uint2(packbf(v[0], v[1]), packbf(v[2], v[3]));
                *(uint2*)(msgs + r * 64 + 4 * l15) = o;
            }
        }
    }
}

// ---------------------------------------------------------------------------
// Launch.
// ---------------------------------------------------------------------------
extern "C" void kernel_launch(void* const* d_in, const int* in_sizes, int n_in,
                              void* d_out, int out_size, void* d_ws, size_t ws_size,
                              hipStream_t stream) {
    (void)in_sizes; (void)n_in; (void)out_size;
    const float* jvals  = (const float*)d_in[0];
    const int*   row    = (const int*)d_in[2];
    const int*   col    = (const int*)d_in[3];
    const float* conv_W = (const float*)d_in[4];
    const float* gru_wi = (const float*)d_in[5];
    const float* gru_wh = (const float*)d_in[6];
    const float* gru_bi = (const float*)d_in[7];
    const float* gru_bh = (const float*)d_in[8];
    const float* mp_W1  = (const float*)d_in[9];
    const float* mp_b1  = (const float*)d_in[10];
    const float* mp_W2  = (const float*)d_in[11];
    const float* mp_b2  = (const float*)d_in[12];
    const float* mp_W3  = (const float*)d_in[13];
    const float* mp_b3  = (const float*)d_in[14];
    const float* ro_b1  = (const float*)d_in[16];
    const float* ro_b2  = (const float*)d_in[18];
    const float* ro_W3  = (const float*)d_in[19];
    const float* ro_b3  = (const float*)d_in[20];

    constexpr size_t OFF_XB  = 35651584ull;
    constexpr size_t OFF_P   = 71303168ull;
    constexpr size_t OFF_W   = 106954752ull;
    constexpr size_t OFF_WCI = 107347968ull;
    constexpr size_t OFF_NM  = 107544576ull;
    constexpr size_t OFF_HR1 = 109641728ull;
    constexpr size_t OFF_HR2 = 111738880ull;
    constexpr size_t OFF_CSR = 113836032ull;
    constexpr size_t OFF_L1  = 114032640ull;
    constexpr size_t OFF_L2  = 115081216ull;
    constexpr size_t OFF_SJ  = 115605504ull;
    constexpr size_t OFF_WH01  = 115638272ull;
    constexpr size_t OFF_WCI01 = 115641344ull;
    constexpr size_t WS_NEED = 115644416ull;
    if (ws_size < WS_NEED) return;

    char* ws = (char*)d_ws;
    ushort* X2   = (ushort*)ws;                 // layer-2 output
    ushort* X1   = (ushort*)(ws + OFF_XB);      // layer-1 output
    ushort* Pn   = (ushort*)(ws + OFF_P);       // node agg (2 MB)
    ushort* msgs = (ushort*)(ws + OFF_P);       // after gru6 (Pn dead)
    ushort* Wb   = (ushort*)(ws + OFF_W);
    ushort* Wci  = (ushort*)(ws + OFF_WCI);     // layer-2 folded conv (384x128)
    ushort* nmb  = (ushort*)(ws + OFF_NM);      // node_msgs, bf16
    ushort* hr1  = (ushort*)(ws + OFF_HR1);
    ushort* hr2  = (ushort*)(ws + OFF_HR2);
    int* deg    = (int*)(ws + OFF_CSR);
    int* start  = deg + 8192;
    int* cur    = deg + 16384;
    int* deg2   = deg + 24576;
    int* start2 = deg + 32768;
    int* cur2   = deg + 40960;
    int* list   = (int*)(ws + OFF_L1);
    int* list2  = (int*)(ws + OFF_L2);
    float* sj    = (float*)(ws + OFF_SJ);
    float* wh01  = (float*)(ws + OFF_WH01);
    float* wci01 = (float*)(ws + OFF_WCI01);

    dim3 blk(256);

    k_setup<<<1030, blk, 0, stream>>>(conv_W, gru_wi, gru_wh, mp_W1, mp_W2, mp_W3,
                                      (const float*)d_in[15], (const float*)d_in[17],
                                      Wb, Wci, wh01, wci01, deg, deg2);
    k_deg_count<<<N_EDGES / 256, blk, 0, stream>>>(row, col, deg, deg2);
    k_scan<<<1, blk, 0, stream>>>(deg, start, cur, deg2, start2, cur2);
    k_fill<<<N_EDGES / 256, blk, 0, stream>>>(row, col, cur, cur2, list, list2);
    k_sort<<<4096, blk, 0, stream>>>(start, deg, start2, deg2, list, list2, jvals, sj);

    // layer 1 (closed form, f32, fused)
    k_l1<<<(N_EDGES + N_NODES) * 64 / 256, blk, 0, stream>>>(jvals, wh01, deg, sj, wci01,
                                                             gru_bi, gru_bh, X1);

    // layer 2  (XCD-swizzled 1-D grid, 512-thread blocks)
    k_agg_nodes<<<N_NODES / 4, blk, 0, stream>>>((uint*)Pn, (const uint*)X1, start, deg, list);
    k_gru6<<<2 * (NTOT / 128), dim3(512), 0, stream>>>(Pn, X1, X2, row, col,
        Wci, Wb + 81920, gru_bi, gru_bh);

    // fused edge MLP -> msgs (bf16)
    k_mlp<<<N_EDGES / 128, dim3(512), 0, stream>>>(
        X2 + (size_t)N_NODES * H, Wb + 131072, Wb + 147456, Wb + 163840,
        mp_b1, mp_b2, mp_b3, msgs);

    // node_msgs = segment_sum(msgs, row) -> bf16
    k_nm_gather<<<N_NODES / 4, blk, 0, stream>>>(nmb, msgs, start2, deg2, list2);

    // readout
    k_gemm2<128, false, true, false><<<N_NODES / 128, blk, 0, stream>>>(
        nmb, Wb + 172032, ro_b1, hr1, 64, 64);
    k_gemm2<128, false, true, false><<<N_NODES / 128, blk, 0, stream>>>(
        hr1, Wb + 180224, ro_b2, hr2, 128, 128);
    k_logits<<<N_NODES / 4, blk, 0, stream>>>(hr2, ro_W3, ro_b3, (float*)d_out);
}